// Round 1
// baseline (22.761 us; speedup 1.0000x reference)
//
#include <hip/hip_runtime.h>
#include <hip/hip_bf16.h>

#define TOKS 2048
#define FEAT 2048
#define NR   128
#define KB   32
#define RB   32
#define TT   32

typedef __attribute__((ext_vector_type(8))) short bf16x8;
typedef __attribute__((ext_vector_type(4))) float f32x4;

__device__ __forceinline__ unsigned short f2bf(float f) {
    unsigned u = __builtin_bit_cast(unsigned, f);
    u += 0x7FFFu + ((u >> 16) & 1u);
    return (unsigned short)(u >> 16);
}

__device__ __forceinline__ bf16x8 pack8(float4 a, float4 b) {
    bf16x8 r;
    r[0] = (short)f2bf(a.x); r[1] = (short)f2bf(a.y);
    r[2] = (short)f2bf(a.z); r[3] = (short)f2bf(a.w);
    r[4] = (short)f2bf(b.x); r[5] = (short)f2bf(b.y);
    r[6] = (short)f2bf(b.z); r[7] = (short)f2bf(b.w);
    return r;
}

__global__ __launch_bounds__(256) void cvt_values_kernel(const float* __restrict__ v,
                                                         unsigned short* __restrict__ o,
                                                         int n) {
    int i = (blockIdx.x * 256 + threadIdx.x) * 4;
    if (i + 3 < n) {
        float4 f = *reinterpret_cast<const float4*>(v + i);
        ushort4 r;
        r.x = f2bf(f.x); r.y = f2bf(f.y); r.z = f2bf(f.z); r.w = f2bf(f.w);
        *reinterpret_cast<ushort4*>(o + i) = r;
    }
}

// Block-sparse MFMA kernel.
//   grid = (TOKS/TT) * (NR/RB) = 64*4 = 256 blocks, 512 threads (8 waves).
//   Each block: stage x[tok0..tok0+32)[0..2048) as bf16 in LDS (XOR-swizzled),
//   then each wave computes 4 r's x 2 token-subtiles of 16.
template<bool VB16>
__global__ __launch_bounds__(512) void bsp_kernel(const float* __restrict__ x,
                                                  const void* __restrict__ values,
                                                  const int* __restrict__ cols,
                                                  const float* __restrict__ bias,
                                                  float* __restrict__ out) {
    __shared__ __align__(16) unsigned short xs[TT * FEAT];   // 128 KiB

    // XCD-partitioned swizzle: xcd = bid&7 gets a contiguous 256-token range
    // (2 MB fp32 x-slice + 2.1 MB bf16 values fit one XCD's 4 MB L2).
    int bid  = blockIdx.x;
    int xcd  = bid & 7, slot = bid >> 3;          // slot 0..31
    int tg   = xcd * 8 + (slot >> 2);             // token group 0..63
    int rg   = slot & 3;                          // r group 0..3
    int tok0 = tg * TT;
    int r0   = rg * RB;
    int tid  = threadIdx.x;

    // ---- stage x tile: fp32 -> bf16, row-major [32][2048] with byte-XOR swizzle ----
    {
        int tr = tid >> 8;          // 0..1 : token parity
        int ch = tid & 255;         // 16B chunk within row (8 bf16)
        #pragma unroll 4
        for (int it = 0; it < TT / 2; ++it) {
            int t = it * 2 + tr;
            const float4* p = reinterpret_cast<const float4*>(
                x + (size_t)(tok0 + t) * FEAT + ch * 8);
            float4 a = p[0], b = p[1];
            int off = (t << 12) + ((ch << 4) ^ ((t & 7) << 4));
            *reinterpret_cast<bf16x8*>(reinterpret_cast<char*>(xs) + off) = pack8(a, b);
        }
    }
    __syncthreads();

    int wave = tid >> 6;
    int lane = tid & 63;
    int n = lane & 15;          // A row (token-in-subtile) == B col (output i) == D col
    int g = lane >> 4;          // k-quarter
    int h = g & 1;              // 8-element half within a 16-wide block
    int q = g >> 1;             // which of the two gathered blocks in this MFMA

    int mrow = n << 12;              // m*4096 bytes (row base in LDS)
    int axor = (n & 7) << 4;         // swizzle term

    #pragma unroll 1
    for (int rr = 0; rr < 4; ++rr) {
        int r = r0 + wave * 4 + rr;
        int cbase = __builtin_amdgcn_readfirstlane(r) * KB;

        bf16x8 bfrag[16];
        int aaddr[16];
        if (VB16) {
            const unsigned short* vbl = reinterpret_cast<const unsigned short*>(values)
                + ((size_t)r << 13) + (q << 8) + (n << 4) + (h << 3);
            #pragma unroll
            for (int t = 0; t < 16; ++t) {
                bfrag[t] = *reinterpret_cast<const bf16x8*>(vbl + t * 512);
                int c0 = cols[cbase + 2 * t];
                int c1 = cols[cbase + 2 * t + 1];
                int c  = q ? c1 : c0;
                aaddr[t] = mrow + (((c << 5) + (h << 4)) ^ axor);
            }
        } else {
            const float* vfl = reinterpret_cast<const float*>(values)
                + ((size_t)r << 13) + (q << 8) + (n << 4) + (h << 3);
            #pragma unroll
            for (int t = 0; t < 16; ++t) {
                const float4* pv = reinterpret_cast<const float4*>(vfl + t * 512);
                bfrag[t] = pack8(pv[0], pv[1]);
                int c0 = cols[cbase + 2 * t];
                int c1 = cols[cbase + 2 * t + 1];
                int c  = q ? c1 : c0;
                aaddr[t] = mrow + (((c << 5) + (h << 4)) ^ axor);
            }
        }

        float fb = bias[(r << 4) + n];

        #pragma unroll
        for (int sx = 0; sx < 2; ++sx) {
            f32x4 acc = {0.f, 0.f, 0.f, 0.f};
            const char* xb = reinterpret_cast<const char*>(xs) + (sx << 16);
            #pragma unroll
            for (int t = 0; t < 16; ++t) {
                bf16x8 af = *reinterpret_cast<const bf16x8*>(xb + aaddr[t]);
                acc = __builtin_amdgcn_mfma_f32_16x16x32_bf16(af, bfrag[t], acc, 0, 0, 0);
            }
            int trow = tok0 + (sx << 4) + (g << 2);
            size_t ob = (size_t)trow * 2048 + (r << 4) + n;
            #pragma unroll
            for (int p = 0; p < 4; ++p)
                out[ob + (size_t)p * 2048] = acc[p] + fb;
        }
    }
}

extern "C" void kernel_launch(void* const* d_in, const int* in_sizes, int n_in,
                              void* d_out, int out_size, void* d_ws, size_t ws_size,
                              hipStream_t stream) {
    const float* x      = (const float*)d_in[0];
    const float* values = (const float*)d_in[1];
    const int*   cols   = (const int*)d_in[2];
    const float* bias   = (const float*)d_in[3];
    float*       out    = (float*)d_out;

    const int nv = NR * KB * 16 * 16;              // 1,048,576 values elements
    const int grid = (TOKS / TT) * (NR / RB);      // 256

    if (ws_size >= (size_t)nv * sizeof(unsigned short)) {
        unsigned short* vb = (unsigned short*)d_ws;
        cvt_values_kernel<<<nv / (256 * 4), 256, 0, stream>>>(values, vb, nv);
        bsp_kernel<true><<<grid, 512, 0, stream>>>(x, vb, cols, bias, out);
    } else {
        bsp_kernel<false><<<grid, 512, 0, stream>>>(x, values, cols, bias, out);
    }
}